// Round 2
// baseline (126.461 us; speedup 1.0000x reference)
//
#include <hip/hip_runtime.h>
#include <cstddef>

// Problem constants (from reference)
#define NN   8
#define AA   16368
#define KK   200
#define BB   20
#define PP   4
#define HW2  16384          // 128*128

// workspace layout (floats)
#define WS_CG    0                    // [N][K][4] gathered coef   (6400 f)
#define WS_S     (NN * KK * 4)        // [N][B][4] per-b coef sums (640 f)
#define WS_PART  (WS_S + NN * BB * 4) // [N] clsloc partials       (8 f)

__device__ __forceinline__ float block_reduce_sum(float v) {
    #pragma unroll
    for (int o = 32; o > 0; o >>= 1) v += __shfl_down(v, o, 64);
    __shared__ float s[4];
    const int lane = threadIdx.x & 63;
    const int wid  = threadIdx.x >> 6;
    if (lane == 0) s[wid] = v;
    __syncthreads();
    float r = 0.f;
    if (threadIdx.x == 0) r = s[0] + s[1] + s[2] + s[3];
    return r;   // valid on thread 0 only
}

__device__ __forceinline__ float smooth_l1(float d) {
    float ad = fabsf(d);
    return (ad < 1.f) ? 0.5f * d * d : ad - 0.5f;
}

// Per image: gather coef -> ws, build S_b = sum_{k: b_k=b} coef_k,
// and compute the full cls+loc loss -> ws partials. Block 0 zeroes out.
__global__ __launch_bounds__(256) void setup_kernel(
        const float* __restrict__ map_class,      // [N,A]
        const float* __restrict__ map_box,        // [N,A,4]
        const float* __restrict__ map_coef,       // [N,A,P]
        const float* __restrict__ anchor_center,  // [A,2]
        const float* __restrict__ anchor_hw,      // [A,2]
        const float* __restrict__ gt_boxes,       // [N,B,4]
        const int*   __restrict__ pos_idx,        // [N,K]
        const int*   __restrict__ neg_idx,        // [N,3K]
        const int*   __restrict__ gt_idx,         // [N,K]
        float* __restrict__ ws,
        float* __restrict__ out) {
    const int n = blockIdx.x;
    const int tid = threadIdx.x;
    __shared__ float sc[KK][4];
    __shared__ int   sb[KK];

    const float EPSF = 1e-7f;
    const float W_CLSPOS = 1.0f / ((float)NN * (float)KK * (float)KK);
    const float W_CLSNEG = 1.0f / ((float)NN * 3.0f * (float)KK * (float)KK);
    const float W_LOC    = 1.0f / ((float)NN * (float)KK);   // ALPHA = 1
    const float LOG10E   = 0.43429448190325176f;

    float acc = 0.f;
    for (int k = tid; k < KK; k += 256) {
        const int a = pos_idx[n * KK + k];
        const int b = gt_idx[n * KK + k];
        const float4 c = *(const float4*)(map_coef + ((size_t)n * AA + a) * PP);
        sc[k][0] = c.x; sc[k][1] = c.y; sc[k][2] = c.z; sc[k][3] = c.w;
        sb[k] = b;
        *(float4*)(ws + WS_CG + ((size_t)n * KK + k) * 4) = c;

        float p = map_class[(size_t)n * AA + a];
        p = fminf(fmaxf(p, EPSF), 1.f - EPSF);
        acc += (-__logf(p)) * W_CLSPOS;

        const float ach = anchor_center[a * 2 + 0];
        const float acw = anchor_center[a * 2 + 1];
        const float ah  = anchor_hw[a * 2 + 0];
        const float aw  = anchor_hw[a * 2 + 1];
        const float* g  = gt_boxes + ((size_t)n * BB + b) * 4;
        const float t0 = (g[0] - ach) / ah;
        const float t1 = (g[1] - acw) / aw;
        const float t2 = __logf(g[2] / ah) * LOG10E;
        const float t3 = __logf(g[3] / aw) * LOG10E;
        const float* pr = map_box + ((size_t)n * AA + a) * 4;
        acc += (smooth_l1(pr[0] - t0) + smooth_l1(pr[1] - t1)
              + smooth_l1(pr[2] - t2) + smooth_l1(pr[3] - t3)) * W_LOC;
    }
    for (int j = tid; j < 3 * KK; j += 256) {
        const int a = neg_idx[n * 3 * KK + j];
        float p = map_class[(size_t)n * AA + a];
        p = fminf(fmaxf(p, EPSF), 1.f - EPSF);
        acc += (-__logf(1.f - p)) * W_CLSNEG;
    }
    __syncthreads();

    if (tid < BB) {
        float s0 = 0.f, s1 = 0.f, s2 = 0.f, s3 = 0.f;
        for (int k = 0; k < KK; ++k) {
            if (sb[k] == tid) { s0 += sc[k][0]; s1 += sc[k][1]; s2 += sc[k][2]; s3 += sc[k][3]; }
        }
        float* S = ws + WS_S + ((size_t)n * BB + tid) * 4;
        S[0] = s0; S[1] = s1; S[2] = s2; S[3] = s3;
    }

    float tot = block_reduce_sum(acc);
    if (tid == 0) {
        ws[WS_PART + n] = tot;
        if (n == 0) out[0] = 0.f;   // mask kernel runs strictly after (stream order)
    }
}

// grid = N * (HW2/256); each thread owns one pixel.
// loss contribution per pixel: sum_k softplus(z_k) - sum_b y_b * (S_b . p)
__global__ __launch_bounds__(256) void mask_loss_kernel(
        const float* __restrict__ proto,      // [N,P,HW2]
        const float* __restrict__ gt_masks,   // [N,B,HW2]
        const float* __restrict__ ws,
        float* __restrict__ out) {
    const int blk = blockIdx.x;
    const int n = blk >> 6;              // HW2/256 = 64 chunks per image
    const int pix = ((blk & 63) << 8) + threadIdx.x;

    const float* pb = proto + (size_t)n * PP * HW2 + pix;
    const float p0 = pb[0];
    const float p1 = pb[HW2];
    const float p2 = pb[2 * HW2];
    const float p3 = pb[3 * HW2];

    // correction term: -sum_b y_b * (S_b . p)
    const float* S  = ws + WS_S + (size_t)n * BB * 4;
    const float* gm = gt_masks + (size_t)n * BB * HW2 + pix;
    float a0 = 0.f, a1 = 0.f, a2 = 0.f, a3 = 0.f;
    #pragma unroll
    for (int b = 0; b < BB; ++b) {
        const float y = gm[(size_t)b * HW2];
        a0 = fmaf(y, S[b * 4 + 0], a0);
        a1 = fmaf(y, S[b * 4 + 1], a1);
        a2 = fmaf(y, S[b * 4 + 2], a2);
        a3 = fmaf(y, S[b * 4 + 3], a3);
    }
    float acc = -(fmaf(a0, p0, fmaf(a1, p1, fmaf(a2, p2, a3 * p3))));

    // main term: sum_k softplus(z_k), coefficients are block-uniform (scalar loads)
    const float* C = ws + WS_CG + (size_t)n * KK * 4;
    const float LN2 = 0.69314718055994531f;
    #pragma unroll 4
    for (int k = 0; k < KK; ++k) {
        const float z = fmaf(C[k * 4 + 0], p0,
                        fmaf(C[k * 4 + 1], p1,
                        fmaf(C[k * 4 + 2], p2, C[k * 4 + 3] * p3)));
        const float e  = __expf(-fabsf(z));
        const float l2 = __log2f(1.f + e);
        acc = fmaf(l2, LN2, acc + fmaxf(z, 0.f));
    }

    float tot = block_reduce_sum(acc);
    if (threadIdx.x == 0) {
        const float W_MSK = 1.0f / ((float)NN * (float)KK * (float)HW2);
        atomicAdd(out, tot * W_MSK);
        if (blk == 0) {
            float c = 0.f;
            #pragma unroll
            for (int i = 0; i < NN; ++i) c += ws[WS_PART + i];
            atomicAdd(out, c);
        }
    }
}

extern "C" void kernel_launch(void* const* d_in, const int* in_sizes, int n_in,
                              void* d_out, int out_size, void* d_ws, size_t ws_size,
                              hipStream_t stream) {
    const float* map_class     = (const float*)d_in[0];
    const float* map_box       = (const float*)d_in[1];
    const float* map_coef      = (const float*)d_in[2];
    const float* proto         = (const float*)d_in[3];
    const float* anchor_center = (const float*)d_in[4];
    const float* anchor_hw     = (const float*)d_in[5];
    const float* gt_boxes      = (const float*)d_in[6];
    const float* gt_masks      = (const float*)d_in[7];
    const int*   pos_idx       = (const int*)d_in[8];
    const int*   neg_idx       = (const int*)d_in[9];
    const int*   gt_idx        = (const int*)d_in[10];
    float* out = (float*)d_out;
    float* ws  = (float*)d_ws;

    setup_kernel<<<NN, 256, 0, stream>>>(map_class, map_box, map_coef,
                                         anchor_center, anchor_hw, gt_boxes,
                                         pos_idx, neg_idx, gt_idx, ws, out);
    mask_loss_kernel<<<NN * (HW2 / 256), 256, 0, stream>>>(proto, gt_masks, ws, out);
}

// Round 3
// 101.230 us; speedup vs baseline: 1.2492x; 1.2492x over previous
//
#include <hip/hip_runtime.h>
#include <cstddef>

// Problem constants (from reference)
#define NN   8
#define AA   16368
#define KK   200
#define BB   20
#define PP   4
#define HW2  16384          // 128*128
#define KCH  4              // K split into 4 chunks of 50
#define KPC  (KK / KCH)     // 50

#define LOG2E 1.44269504088896340736f
#define LN2   0.69314718055994530942f

__device__ __forceinline__ float block_reduce_sum(float v) {
    #pragma unroll
    for (int o = 32; o > 0; o >>= 1) v += __shfl_down(v, o, 64);
    __shared__ float s[4];
    const int lane = threadIdx.x & 63;
    const int wid  = threadIdx.x >> 6;
    if (lane == 0) s[wid] = v;
    __syncthreads();
    float r = 0.f;
    if (threadIdx.x == 0) r = s[0] + s[1] + s[2] + s[3];
    return r;   // valid on thread 0 only
}

__device__ __forceinline__ float smooth_l1(float d) {
    float ad = fabsf(d);
    return (ad < 1.f) ? 0.5f * d * d : ad - 0.5f;
}

__global__ void zero_out_kernel(float* out) { out[0] = 0.f; }

// grid = 520 blocks of 256 threads.
//   blocks [0,512): mask loss. block = (kchunk 0..3) x (pixchunk 0..127);
//     pixchunk = image n (0..7) x 16 chunks of 1024 pixels (4 per thread).
//     Each block gathers its 50 coefs (pre-scaled by log2e) into LDS; the
//     kchunk==0 blocks additionally build S_b = sum_{k: b_k=b} coef_k and
//     apply the exact-algebra correction  -sum_b y_b (S_b . p) so the per-k
//     target term never touches gt_masks again.
//     BCE(sigmoid(z),y) = softplus(z) - y*z  (clip inactive: |z| << 16.1)
//   blocks [512,520): classification + localization for image n = blk-512.
__global__ __launch_bounds__(256) void fused_loss_kernel(
        const float* __restrict__ map_class,      // [N,A]
        const float* __restrict__ map_box,        // [N,A,4]
        const float* __restrict__ map_coef,       // [N,A,P]
        const float* __restrict__ proto,          // [N,P,HW2]
        const float* __restrict__ anchor_center,  // [A,2]
        const float* __restrict__ anchor_hw,      // [A,2]
        const float* __restrict__ gt_boxes,       // [N,B,4]
        const float* __restrict__ gt_masks,       // [N,B,HW2]
        const int*   __restrict__ pos_idx,        // [N,K]
        const int*   __restrict__ neg_idx,        // [N,3K]
        const int*   __restrict__ gt_idx,         // [N,K]
        float* __restrict__ out) {
    const int blk = blockIdx.x;
    const int tid = threadIdx.x;

    if (blk >= KCH * 128) {
        // ---------------- cls + loc for one image ----------------
        const int n = blk - KCH * 128;
        const float EPSF = 1e-7f;
        const float W_CLSPOS = 1.0f / ((float)NN * (float)KK * (float)KK);
        const float W_CLSNEG = 1.0f / ((float)NN * 3.0f * (float)KK * (float)KK);
        const float W_LOC    = 1.0f / ((float)NN * (float)KK);   // ALPHA = 1
        const float LOG10E   = 0.43429448190325176f;

        float acc = 0.f;
        for (int k = tid; k < KK; k += 256) {
            const int a = pos_idx[n * KK + k];
            const int b = gt_idx[n * KK + k];
            float p = map_class[(size_t)n * AA + a];
            p = fminf(fmaxf(p, EPSF), 1.f - EPSF);
            acc += (-__logf(p)) * W_CLSPOS;

            const float ach = anchor_center[a * 2 + 0];
            const float acw = anchor_center[a * 2 + 1];
            const float ah  = anchor_hw[a * 2 + 0];
            const float aw  = anchor_hw[a * 2 + 1];
            const float* g  = gt_boxes + ((size_t)n * BB + b) * 4;
            const float t0 = (g[0] - ach) / ah;
            const float t1 = (g[1] - acw) / aw;
            const float t2 = __logf(g[2] / ah) * LOG10E;
            const float t3 = __logf(g[3] / aw) * LOG10E;
            const float* pr = map_box + ((size_t)n * AA + a) * 4;
            acc += (smooth_l1(pr[0] - t0) + smooth_l1(pr[1] - t1)
                  + smooth_l1(pr[2] - t2) + smooth_l1(pr[3] - t3)) * W_LOC;
        }
        for (int j = tid; j < 3 * KK; j += 256) {
            const int a = neg_idx[n * 3 * KK + j];
            float p = map_class[(size_t)n * AA + a];
            p = fminf(fmaxf(p, EPSF), 1.f - EPSF);
            acc += (-__logf(1.f - p)) * W_CLSNEG;
        }
        float tot = block_reduce_sum(acc);
        if (tid == 0) atomicAdd(out, tot);
        return;
    }

    // ---------------- mask loss ----------------
    const int kc = blk >> 7;              // 0..3
    const int pc = blk & 127;             // 0..127
    const int n  = pc >> 4;               // image
    const int ch = pc & 15;               // 1024-pixel chunk

    __shared__ float4 sC[KPC];            // this chunk's coefs, pre-scaled log2e
    __shared__ float  S[BB][4];           // per-gt coef sums (kc==0 only)

    if (kc == 0) {
        if (tid < BB * 4) ((float*)S)[tid] = 0.f;
        __syncthreads();
        if (tid < KK) {
            const int a = pos_idx[n * KK + tid];
            const float4 c = *(const float4*)(map_coef + ((size_t)n * AA + a) * 4);
            if (tid < KPC) {
                float4 cl;
                cl.x = c.x * LOG2E; cl.y = c.y * LOG2E;
                cl.z = c.z * LOG2E; cl.w = c.w * LOG2E;
                sC[tid] = cl;
            }
            const int b = gt_idx[n * KK + tid];
            atomicAdd(&S[b][0], c.x); atomicAdd(&S[b][1], c.y);
            atomicAdd(&S[b][2], c.z); atomicAdd(&S[b][3], c.w);
        }
    } else {
        if (tid < KPC) {
            const int a = pos_idx[n * KK + kc * KPC + tid];
            const float4 c = *(const float4*)(map_coef + ((size_t)n * AA + a) * 4);
            float4 cl;
            cl.x = c.x * LOG2E; cl.y = c.y * LOG2E;
            cl.z = c.z * LOG2E; cl.w = c.w * LOG2E;
            sC[tid] = cl;
        }
    }
    __syncthreads();

    const int vidx = ch * 256 + tid;      // float4 index within one [HW2] plane
    const float4* pr = (const float4*)(proto + (size_t)n * PP * HW2);
    const float4 p0 = pr[0 * (HW2 / 4) + vidx];
    const float4 p1 = pr[1 * (HW2 / 4) + vidx];
    const float4 p2 = pr[2 * (HW2 / 4) + vidx];
    const float4 p3 = pr[3 * (HW2 / 4) + vidx];

    // correction term: -sum_b y_b * (S_b . p), per pixel; kc==0 blocks only
    float corr0 = 0.f, corr1 = 0.f, corr2 = 0.f, corr3 = 0.f;
    if (kc == 0) {
        const float4* gm = (const float4*)(gt_masks + (size_t)n * BB * HW2);
        float ax0=0,ax1=0,ax2=0,ax3=0, ay0=0,ay1=0,ay2=0,ay3=0;
        float az0=0,az1=0,az2=0,az3=0, aw0=0,aw1=0,aw2=0,aw3=0;
        #pragma unroll
        for (int b = 0; b < BB; ++b) {
            const float4 y = gm[(size_t)b * (HW2 / 4) + vidx];
            const float s0 = S[b][0], s1 = S[b][1], s2 = S[b][2], s3 = S[b][3];
            ax0 = fmaf(y.x, s0, ax0); ay0 = fmaf(y.x, s1, ay0);
            az0 = fmaf(y.x, s2, az0); aw0 = fmaf(y.x, s3, aw0);
            ax1 = fmaf(y.y, s0, ax1); ay1 = fmaf(y.y, s1, ay1);
            az1 = fmaf(y.y, s2, az1); aw1 = fmaf(y.y, s3, aw1);
            ax2 = fmaf(y.z, s0, ax2); ay2 = fmaf(y.z, s1, ay2);
            az2 = fmaf(y.z, s2, az2); aw2 = fmaf(y.z, s3, aw2);
            ax3 = fmaf(y.w, s0, ax3); ay3 = fmaf(y.w, s1, ay3);
            az3 = fmaf(y.w, s2, az3); aw3 = fmaf(y.w, s3, aw3);
        }
        corr0 = fmaf(ax0, p0.x, fmaf(ay0, p1.x, fmaf(az0, p2.x, aw0 * p3.x)));
        corr1 = fmaf(ax1, p0.y, fmaf(ay1, p1.y, fmaf(az1, p2.y, aw1 * p3.y)));
        corr2 = fmaf(ax2, p0.z, fmaf(ay2, p1.z, fmaf(az2, p2.z, aw2 * p3.z)));
        corr3 = fmaf(ax3, p0.w, fmaf(ay3, p1.w, fmaf(az3, p2.w, aw3 * p3.w)));
    }

    // main term in log2 domain: sum_k softplus2(zl) ; softplus = LN2 * that
    float sl0 = 0.f, sl1 = 0.f, sl2 = 0.f, sl3 = 0.f;
    #pragma unroll 2
    for (int k = 0; k < KPC; ++k) {
        const float4 c = sC[k];
        const float z0 = fmaf(c.x, p0.x, fmaf(c.y, p1.x, fmaf(c.z, p2.x, c.w * p3.x)));
        const float z1 = fmaf(c.x, p0.y, fmaf(c.y, p1.y, fmaf(c.z, p2.y, c.w * p3.y)));
        const float z2 = fmaf(c.x, p0.z, fmaf(c.y, p1.z, fmaf(c.z, p2.z, c.w * p3.z)));
        const float z3 = fmaf(c.x, p0.w, fmaf(c.y, p1.w, fmaf(c.z, p2.w, c.w * p3.w)));
        sl0 += fmaxf(z0, 0.f) + __log2f(1.f + __builtin_amdgcn_exp2f(-fabsf(z0)));
        sl1 += fmaxf(z1, 0.f) + __log2f(1.f + __builtin_amdgcn_exp2f(-fabsf(z1)));
        sl2 += fmaxf(z2, 0.f) + __log2f(1.f + __builtin_amdgcn_exp2f(-fabsf(z2)));
        sl3 += fmaxf(z3, 0.f) + __log2f(1.f + __builtin_amdgcn_exp2f(-fabsf(z3)));
    }

    const float v = LN2 * (sl0 + sl1 + sl2 + sl3) - (corr0 + corr1 + corr2 + corr3);
    float tot = block_reduce_sum(v);
    if (tid == 0) {
        const float W_MSK = 1.0f / ((float)NN * (float)KK * (float)HW2);
        atomicAdd(out, tot * W_MSK);
    }
}

extern "C" void kernel_launch(void* const* d_in, const int* in_sizes, int n_in,
                              void* d_out, int out_size, void* d_ws, size_t ws_size,
                              hipStream_t stream) {
    const float* map_class     = (const float*)d_in[0];
    const float* map_box       = (const float*)d_in[1];
    const float* map_coef      = (const float*)d_in[2];
    const float* proto         = (const float*)d_in[3];
    const float* anchor_center = (const float*)d_in[4];
    const float* anchor_hw     = (const float*)d_in[5];
    const float* gt_boxes      = (const float*)d_in[6];
    const float* gt_masks      = (const float*)d_in[7];
    const int*   pos_idx       = (const int*)d_in[8];
    const int*   neg_idx       = (const int*)d_in[9];
    const int*   gt_idx        = (const int*)d_in[10];
    float* out = (float*)d_out;

    zero_out_kernel<<<1, 1, 0, stream>>>(out);
    fused_loss_kernel<<<KCH * 128 + NN, 256, 0, stream>>>(
        map_class, map_box, map_coef, proto, anchor_center, anchor_hw,
        gt_boxes, gt_masks, pos_idx, neg_idx, gt_idx, out);
}